// Round 2
// baseline (355.088 us; speedup 1.0000x reference)
//
#include <hip/hip_runtime.h>

// Centroids: argmin_c ||latent[r] - coords[c]||^2, 131072 rows x 2048 coords, D=128.
//
// prep_coords: coords -> bf16 hi/lo "B images", XOR-swizzled granules (contiguous
//   LDS copy AND conflict-free frag ds_read_b128), + c2, + counter=0.
// centroid_fast:
//   - 64-row waves (mt=0..3), dbuf LDS staged with global_load_lds w=16 and
//     counted s_waitcnt vmcnt(8) (R1).
//   - R2: in-wave software pipeline. Acc ping-pong accA/accB: the 16-slot argmin
//     epilogue of nt-1 is sliced 4-slots-per-ks and interleaved under nt's MFMA
//     phase (registers only -> legally crosses the chunk barrier, nt=3's epilogue
//     runs under next chunk's nt=0 MFMAs). B-fragments ds_read-prefetched one ks
//     ahead so the 12-MFMA group never waits on lgkm. fmed3 for 2nd-best (4 ops
//     per score). Targets the 50% MFMA-pipe idle measured in R1 (MfmaUtil 45%).
//   - c2 folded into MFMA acc init (acc = -0.5*c2, argmax of dot-c2/2).
//     MARGIN_H = 0.01 half-scale == 0.02 full-scale.
// refine_fp64: rows with gap < margin recomputed exactly in fp64 (~0.5%).
//
// ws layout (bytes): 0 c2 | 8192 counter | 16384 worklist(128KB) |
//                    262144 Bh (512KB) | 786432 Bl (512KB) | end 1310720

constexpr int D = 128;
constexpr int C = 2048;
constexpr int NCH = 64;            // coords per chunk
constexpr int NCHUNKS = C / NCH;   // 32
constexpr float MARGIN_H = 0.01f;  // half-scale: bf16x2 err ~2.5e-3 -> 4x headroom
constexpr int WL_CAP = 32768;

constexpr size_t WS_CNT = 8192;
constexpr size_t WS_WL  = 16384;
constexpr size_t WS_BH  = 262144;
constexpr size_t WS_BL  = 786432;

typedef __attribute__((ext_vector_type(8))) short short8;
typedef __attribute__((ext_vector_type(4))) float f32x4;
typedef unsigned int u32;

__device__ inline unsigned short bf16_rne(float x) {
    unsigned u = __float_as_uint(x);
    u += 0x7FFFu + ((u >> 16) & 1u);
    return (unsigned short)(u >> 16);
}
__device__ inline float bf16_to_f(unsigned short h) {
    return __uint_as_float(((unsigned)h) << 16);
}
__device__ inline void split8(const float* v, short8* hi, short8* lo) {
#pragma unroll
    for (int j = 0; j < 8; ++j) {
        unsigned short h = bf16_rne(v[j]);
        (*hi)[j] = (short)h;
        (*lo)[j] = (short)bf16_rne(v[j] - bf16_to_f(h));
    }
}

// async global->LDS, 16B per lane. LDS dest is wave-uniform base + lane*16,
// which our tid*16-contiguous layout satisfies.
__device__ __forceinline__ void gl_lds16(const void* g, void* l) {
    __builtin_amdgcn_global_load_lds(
        (const __attribute__((address_space(1))) u32*)g,
        (__attribute__((address_space(3))) u32*)l, 16, 0, 0);
}

// ---------------- prep: B images + c2 ----------------
// 32768 threads: thread t -> coord c = t>>4, k-granule k8 = t&15.
// Image: chunk ch = c>>6, nl = c&63; granule g = nl*16 + (k8 ^ (nl&15)).
__global__ void prep_coords(const float* __restrict__ coords,
                            unsigned short* __restrict__ Bh,
                            unsigned short* __restrict__ Bl,
                            float* __restrict__ c2, int* __restrict__ counter) {
    int t = blockIdx.x * blockDim.x + threadIdx.x;
    if (t == 0) *counter = 0;
    if (t >= C * 16) return;
    int c  = t >> 4;
    int k8 = t & 15;
    float v[8];
    *(float4*)(v)     = *(const float4*)(coords + (size_t)c * D + k8 * 8);
    *(float4*)(v + 4) = *(const float4*)(coords + (size_t)c * D + k8 * 8 + 4);
    short8 hi, lo;
    split8(v, &hi, &lo);
    int ch = c >> 6, nl = c & 63;
    size_t off = (size_t)ch * (NCH * 128) + ((size_t)nl * 16 + (k8 ^ (nl & 15))) * 8;
    *(short8*)(Bh + off) = hi;
    *(short8*)(Bl + off) = lo;
    float p = 0.f;
#pragma unroll
    for (int j = 0; j < 8; ++j) p = fmaf(v[j], v[j], p);
#pragma unroll
    for (int m = 1; m <= 8; m <<= 1) p += __shfl_xor(p, m, 64);
    if (k8 == 0) c2[c] = p;
}

// ---------------- main kernel ----------------

// epilogue slice: 4 slots (KS*4+r) of pending acc set P, col index png.
// b2 via med3: second-largest of (a, b1, b2) == median when b2 <= b1.
#define EPI_SLICE(P, KS)                                                  \
    do {                                                                  \
        _Pragma("unroll") for (int r = 0; r < 4; ++r) {                   \
            const int slot = (KS) * 4 + r;                                \
            float a = P[KS][r];                                           \
            b2[slot] = __builtin_amdgcn_fmed3f(a, b1[slot], b2[slot]);    \
            bool gt = a > b1[slot];                                       \
            b1[slot] = fmaxf(a, b1[slot]);                                \
            bidx[slot] = gt ? png : bidx[slot];                           \
        }                                                                 \
    } while (0)

// one nt step: init acc C with -c2/2, 4 ks groups of 12 MFMAs each, with
// (a) B-frag prefetch one step ahead and (b) epilogue slices of pending P.
#define DO_NT(NT, CACC, PACC)                                                  \
    do {                                                                       \
        const int nl_ = (NT) * 16 + lr;                                        \
        const float mh_ = -0.5f * sc2[chbase + nl_];                           \
        _Pragma("unroll") for (int mt = 0; mt < 4; ++mt)                       \
            CACC[mt] = (f32x4){mh_, mh_, mh_, mh_};                            \
        _Pragma("unroll") for (int ks = 0; ks < 4; ++ks) {                     \
            short8 nh_, nl2_;                                                  \
            constexpr bool last_ = ((NT) == 3);                                \
            if (ks < 3) {                                                      \
                const int e_ = nl_ * 128 + ((((ks + 1) * 4) | q) ^ lr) * 8;    \
                nh_  = *(const short8*)(&Bh[buf][e_]);                         \
                nl2_ = *(const short8*)(&Bl[buf][e_]);                         \
            } else if (!last_) {                                               \
                const int e_ = (nl_ + 16) * 128 + (q ^ lr) * 8;                \
                nh_  = *(const short8*)(&Bh[buf][e_]);                         \
                nl2_ = *(const short8*)(&Bl[buf][e_]);                         \
            }                                                                  \
            EPI_SLICE(PACC, ks);                                               \
            _Pragma("unroll") for (int mt = 0; mt < 4; ++mt)                   \
                CACC[mt] = __builtin_amdgcn_mfma_f32_16x16x32_bf16(            \
                    Ah[mt][ks], bch, CACC[mt], 0, 0, 0);                       \
            _Pragma("unroll") for (int mt = 0; mt < 4; ++mt)                   \
                CACC[mt] = __builtin_amdgcn_mfma_f32_16x16x32_bf16(            \
                    Ah[mt][ks], bcl, CACC[mt], 0, 0, 0);                       \
            _Pragma("unroll") for (int mt = 0; mt < 4; ++mt)                   \
                CACC[mt] = __builtin_amdgcn_mfma_f32_16x16x32_bf16(            \
                    Al[mt][ks], bch, CACC[mt], 0, 0, 0);                       \
            if (ks < 3 || !last_) { bch = nh_; bcl = nl2_; }                   \
        }                                                                      \
        png = chbase + nl_;                                                    \
    } while (0)

__global__ __launch_bounds__(256, 2) void centroid_fast(
        const float* __restrict__ latent,
        const unsigned short* __restrict__ Bh_img,
        const unsigned short* __restrict__ Bl_img,
        const float* __restrict__ c2g,
        int* __restrict__ out,
        int* __restrict__ counter,
        int* __restrict__ worklist) {
    // 2x16KB hi + 2x16KB lo (double-buffered) + full c2 table = 72 KB -> 2 blocks/CU
    __shared__ __align__(16) unsigned short Bh[2][NCH * 128], Bl[2][NCH * 128];
    __shared__ __align__(16) float sc2[C];

    const int tid  = threadIdx.x;
    const int wid  = tid >> 6;            // wave 0..3 -> rows wid*64..wid*64+63
    const int lane = tid & 63;
    const int q    = lane >> 4, lr = lane & 15;
    const int row_block = blockIdx.x * 256;

    // ---- prologue: stage chunk 0 (async), c2 table, A fragments ----
    {
        const unsigned short* sh = Bh_img;
        const unsigned short* sl = Bl_img;
#pragma unroll
        for (int i = 0; i < 4; ++i) {
            int e = (i * 256 + tid) * 8;
            gl_lds16(sh + e, &Bh[0][e]);
            gl_lds16(sl + e, &Bl[0][e]);
        }
    }
#pragma unroll
    for (int i = 0; i < 2; ++i) {
        int e = (i * 256 + tid) * 4;
        *(float4*)(sc2 + e) = *(const float4*)(c2g + e);
    }

    // A fragments: lane holds A[m = lr][k = ks*32 + q*8 .. +8] for rows
    // wid*64 + mt*16 + lr. 32 short8 = 128 VGPRs long-lived.
    short8 Ah[4][4], Al[4][4];
#pragma unroll
    for (int mt = 0; mt < 4; ++mt) {
        const float* rp = latent + (size_t)(row_block + wid * 64 + mt * 16 + lr) * D;
#pragma unroll
        for (int ks = 0; ks < 4; ++ks) {
            float v[8];
            *(float4*)(v)     = *(const float4*)(rp + ks * 32 + q * 8);
            *(float4*)(v + 4) = *(const float4*)(rp + ks * 32 + q * 8 + 4);
            split8(v, &Ah[mt][ks], &Al[mt][ks]);
        }
    }

    // argmax state over a = dot - 0.5*c2 (== argmin distance), 16 slots
    float b1[16], b2[16];
    int   bidx[16];
#pragma unroll
    for (int s = 0; s < 16; ++s) { b1[s] = -3.4e38f; b2[s] = -3.4e38f; bidx[s] = 0; }

    // pending-epilogue state: accB primed to -inf (harmless first epilogue)
    f32x4 accA[4], accB[4];
#pragma unroll
    for (int mt = 0; mt < 4; ++mt) accB[mt] = (f32x4){-3.4e38f, -3.4e38f, -3.4e38f, -3.4e38f};
    int png = 0;
    short8 bch, bcl;

    __syncthreads();   // full drain: chunk-0 stage + sc2 + A loads all visible

    for (int ch = 0; ch < NCHUNKS; ++ch) {
        const int buf = ch & 1;
        const int chbase = ch * NCH;
        // issue next chunk's stage FIRST, then counted wait on current chunk's 8
        if (ch + 1 < NCHUNKS) {
            const unsigned short* sh = Bh_img + (size_t)(ch + 1) * (NCH * 128);
            const unsigned short* sl = Bl_img + (size_t)(ch + 1) * (NCH * 128);
#pragma unroll
            for (int i = 0; i < 4; ++i) {
                int e = (i * 256 + tid) * 8;
                gl_lds16(sh + e, &Bh[buf ^ 1][e]);
                gl_lds16(sl + e, &Bl[buf ^ 1][e]);
            }
            asm volatile("s_waitcnt vmcnt(8)" ::: "memory");  // cur done, next in flight
        } else {
            asm volatile("s_waitcnt vmcnt(0)" ::: "memory");
        }
        __builtin_amdgcn_s_barrier();

        // prime (nt=0, ks=0) fragments
        {
            const int e0 = lr * 128 + (q ^ lr) * 8;
            bch = *(const short8*)(&Bh[buf][e0]);
            bcl = *(const short8*)(&Bl[buf][e0]);
        }
        DO_NT(0, accA, accB);
        DO_NT(1, accB, accA);
        DO_NT(2, accA, accB);
        DO_NT(3, accB, accA);

        __builtin_amdgcn_s_barrier();   // all reads of buf done before it's restaged
    }

    // final pending epilogue (accB from last chunk's nt=3)
#pragma unroll
    for (int ks = 0; ks < 4; ++ks) EPI_SLICE(accB, ks);

    // butterfly over the 16 col-residue lanes (max semantics).
    // No index tie-break: equal scores -> gap 0 < margin -> exact refine.
#pragma unroll
    for (int m = 1; m <= 8; m <<= 1) {
#pragma unroll
        for (int s = 0; s < 16; ++s) {
            float oa = __shfl_xor(b1[s], m, 64);
            float ob = __shfl_xor(b2[s], m, 64);
            int   oi = __shfl_xor(bidx[s], m, 64);
            float mn = fminf(b1[s], oa);
            b2[s] = fmaxf(fmaxf(b2[s], ob), mn);
            bool take = oa > b1[s];
            b1[s]   = take ? oa : b1[s];
            bidx[s] = take ? oi : bidx[s];
        }
    }
    // slot s canonical in lane lr==s; row = wid*64 + (s>>2)*16 + q*4 + (s&3)
#pragma unroll
    for (int s = 0; s < 16; ++s) {
        if (lr == s) {
            int row = row_block + wid * 64 + (s >> 2) * 16 + q * 4 + (s & 3);
            out[row] = bidx[s];
            if (b1[s] - b2[s] < MARGIN_H) {
                int w = atomicAdd(counter, 1);
                if (w < WL_CAP) worklist[w] = row;
            }
        }
    }
}

// ---------------- fp64 refine ----------------

__global__ __launch_bounds__(256) void refine_fp64(
        const float* __restrict__ latent, const float* __restrict__ coords,
        const int* __restrict__ worklist, const int* __restrict__ counter,
        int wl_cap, int* __restrict__ out) {
    __shared__ float  xs[D];
    __shared__ double rv[256];
    __shared__ int    ri[256];

    int n = *counter;
    if (n > wl_cap) n = wl_cap;

    for (int wi = blockIdx.x; wi < n; wi += gridDim.x) {
        int row = worklist[wi];
        if (threadIdx.x < D)
            xs[threadIdx.x] = latent[(size_t)row * D + threadIdx.x];
        __syncthreads();

        double best = 1.0e300;
        int    bix  = 0;
        for (int c = threadIdx.x; c < C; c += 256) {
            const float4* cp = (const float4*)(coords + (size_t)c * D);
            // 4 independent accumulators: breaks the 512-deep dependent fma chain
            double s0 = 0.0, s1 = 0.0, s2 = 0.0, s3 = 0.0;
#pragma unroll 8
            for (int k4 = 0; k4 < 32; ++k4) {
                float4 v = cp[k4];
                double d0 = (double)xs[k4 * 4 + 0] - (double)v.x;
                double d1 = (double)xs[k4 * 4 + 1] - (double)v.y;
                double d2 = (double)xs[k4 * 4 + 2] - (double)v.z;
                double d3 = (double)xs[k4 * 4 + 3] - (double)v.w;
                s0 = fma(d0, d0, s0); s1 = fma(d1, d1, s1);
                s2 = fma(d2, d2, s2); s3 = fma(d3, d3, s3);
            }
            double s = (s0 + s1) + (s2 + s3);
            if (s < best) { best = s; bix = c; }
        }
        rv[threadIdx.x] = best;
        ri[threadIdx.x] = bix;
        __syncthreads();
        for (int off = 128; off > 0; off >>= 1) {
            if (threadIdx.x < off) {
                double ov = rv[threadIdx.x + off];
                int    oi = ri[threadIdx.x + off];
                if (ov < rv[threadIdx.x] ||
                    (ov == rv[threadIdx.x] && oi < ri[threadIdx.x])) {
                    rv[threadIdx.x] = ov;
                    ri[threadIdx.x] = oi;
                }
            }
            __syncthreads();
        }
        if (threadIdx.x == 0) out[row] = ri[0];
        __syncthreads();
    }
}

extern "C" void kernel_launch(void* const* d_in, const int* in_sizes, int n_in,
                              void* d_out, int out_size, void* d_ws, size_t ws_size,
                              hipStream_t stream) {
    const float* latent = (const float*)d_in[0];
    const float* coords = (const float*)d_in[1];
    int*         out    = (int*)d_out;

    char* ws = (char*)d_ws;
    float* c2      = (float*)ws;
    int*   counter = (int*)(ws + WS_CNT);
    int*   wl      = (int*)(ws + WS_WL);
    unsigned short* Bh = (unsigned short*)(ws + WS_BH);
    unsigned short* Bl = (unsigned short*)(ws + WS_BL);
    const int n_rows = in_sizes[0] / D;   // 131072

    prep_coords<<<(C * 16) / 256, 256, 0, stream>>>(coords, Bh, Bl, c2, counter);
    centroid_fast<<<n_rows / 256, 256, 0, stream>>>(latent, Bh, Bl, c2, out,
                                                    counter, wl);
    refine_fp64<<<608, 256, 0, stream>>>(latent, coords, wl, counter, WL_CAP, out);
}

// Round 3
// 292.673 us; speedup vs baseline: 1.2133x; 1.2133x over previous
//
#include <hip/hip_runtime.h>

// Centroids: argmin_c ||latent[r] - coords[c]||^2, 131072 rows x 2048 coords, D=128.
//
// prep_coords: coords -> bf16 hi/lo "B images", XOR-swizzled granules (contiguous
//   LDS copy AND conflict-free frag ds_read_b128), + c2, + counter=0.
// centroid_fast:
//   - 64-row waves (mt=0..3), dbuf LDS staged with global_load_lds w=16 and
//     counted s_waitcnt vmcnt(8) (R1 structure, 200us/45% MfmaUtil, no spill).
//   - R2 lesson: acc ping-pong + B-prefetch spilled (WRITE_SIZE 3.6->82 MB) ->
//     reverted. Kept its correctness-validated med3 epilogue + no-tiebreak.
//   - R3: overlap fixes with ZERO added registers:
//     (a) de-phase co-resident blocks: half-chunk entry sleep for blocks with
//         (bid^bid>>8)&1 — identical-cadence block pairs on one CU phase-lock,
//         idling the MFMA pipe during common stall regions (theory for the
//         ~50% idle at 45% MfmaUtil).
//     (b) s_setprio(1) around the MFMA section of each nt (T5): favors the
//         MFMA-holding wave in issue arbitration vs the other block's wave.
//   - c2 folded into MFMA acc init (acc = -0.5*c2, argmax of dot-c2/2).
//     MARGIN_H = 0.01 half-scale == 0.02 full-scale.
// refine_fp64: rows with gap < margin recomputed exactly in fp64 (~0.2-0.5%).
//
// ws layout (bytes): 0 c2 | 8192 counter | 16384 worklist(128KB) |
//                    262144 Bh (512KB) | 786432 Bl (512KB) | end 1310720

constexpr int D = 128;
constexpr int C = 2048;
constexpr int NCH = 64;            // coords per chunk
constexpr int NCHUNKS = C / NCH;   // 32
constexpr float MARGIN_H = 0.01f;  // half-scale: bf16x2 err ~2.5e-3 -> 4x headroom
constexpr int WL_CAP = 32768;

constexpr size_t WS_CNT = 8192;
constexpr size_t WS_WL  = 16384;
constexpr size_t WS_BH  = 262144;
constexpr size_t WS_BL  = 786432;

typedef __attribute__((ext_vector_type(8))) short short8;
typedef __attribute__((ext_vector_type(4))) float f32x4;
typedef unsigned int u32;

__device__ inline unsigned short bf16_rne(float x) {
    unsigned u = __float_as_uint(x);
    u += 0x7FFFu + ((u >> 16) & 1u);
    return (unsigned short)(u >> 16);
}
__device__ inline float bf16_to_f(unsigned short h) {
    return __uint_as_float(((unsigned)h) << 16);
}
__device__ inline void split8(const float* v, short8* hi, short8* lo) {
#pragma unroll
    for (int j = 0; j < 8; ++j) {
        unsigned short h = bf16_rne(v[j]);
        (*hi)[j] = (short)h;
        (*lo)[j] = (short)bf16_rne(v[j] - bf16_to_f(h));
    }
}

// async global->LDS, 16B per lane. LDS dest is wave-uniform base + lane*16,
// which our tid*16-contiguous layout satisfies.
__device__ __forceinline__ void gl_lds16(const void* g, void* l) {
    __builtin_amdgcn_global_load_lds(
        (const __attribute__((address_space(1))) u32*)g,
        (__attribute__((address_space(3))) u32*)l, 16, 0, 0);
}

// ---------------- prep: B images + c2 ----------------
// 32768 threads: thread t -> coord c = t>>4, k-granule k8 = t&15.
// Image: chunk ch = c>>6, nl = c&63; granule g = nl*16 + (k8 ^ (nl&15)).
__global__ void prep_coords(const float* __restrict__ coords,
                            unsigned short* __restrict__ Bh,
                            unsigned short* __restrict__ Bl,
                            float* __restrict__ c2, int* __restrict__ counter) {
    int t = blockIdx.x * blockDim.x + threadIdx.x;
    if (t == 0) *counter = 0;
    if (t >= C * 16) return;
    int c  = t >> 4;
    int k8 = t & 15;
    float v[8];
    *(float4*)(v)     = *(const float4*)(coords + (size_t)c * D + k8 * 8);
    *(float4*)(v + 4) = *(const float4*)(coords + (size_t)c * D + k8 * 8 + 4);
    short8 hi, lo;
    split8(v, &hi, &lo);
    int ch = c >> 6, nl = c & 63;
    size_t off = (size_t)ch * (NCH * 128) + ((size_t)nl * 16 + (k8 ^ (nl & 15))) * 8;
    *(short8*)(Bh + off) = hi;
    *(short8*)(Bl + off) = lo;
    float p = 0.f;
#pragma unroll
    for (int j = 0; j < 8; ++j) p = fmaf(v[j], v[j], p);
#pragma unroll
    for (int m = 1; m <= 8; m <<= 1) p += __shfl_xor(p, m, 64);
    if (k8 == 0) c2[c] = p;
}

// ---------------- main kernel ----------------

__global__ __launch_bounds__(256, 2) void centroid_fast(
        const float* __restrict__ latent,
        const unsigned short* __restrict__ Bh_img,
        const unsigned short* __restrict__ Bl_img,
        const float* __restrict__ c2g,
        int* __restrict__ out,
        int* __restrict__ counter,
        int* __restrict__ worklist) {
    // 2x16KB hi + 2x16KB lo (double-buffered) + full c2 table = 72 KB -> 2 blocks/CU
    __shared__ __align__(16) unsigned short Bh[2][NCH * 128], Bl[2][NCH * 128];
    __shared__ __align__(16) float sc2[C];

    const int tid  = threadIdx.x;
    const int wid  = tid >> 6;            // wave 0..3 -> rows wid*64..wid*64+63
    const int lane = tid & 63;
    const int q    = lane >> 4, lr = lane & 15;
    const int row_block = blockIdx.x * 256;

    // de-phase co-resident blocks: ~half a chunk (~7k cyc) one-time sleep.
    // XOR of bit0 and bit8 staggers both (2i,2i+1) and (i,i+256) pairings.
    if ((blockIdx.x ^ (blockIdx.x >> 8)) & 1) {
#pragma unroll
        for (int i = 0; i < 14; ++i) __builtin_amdgcn_s_sleep(8);
    }

    // ---- prologue: stage chunk 0 (async), c2 table, A fragments ----
    {
        const unsigned short* sh = Bh_img;
        const unsigned short* sl = Bl_img;
#pragma unroll
        for (int i = 0; i < 4; ++i) {
            int e = (i * 256 + tid) * 8;
            gl_lds16(sh + e, &Bh[0][e]);
            gl_lds16(sl + e, &Bl[0][e]);
        }
    }
#pragma unroll
    for (int i = 0; i < 2; ++i) {
        int e = (i * 256 + tid) * 4;
        *(float4*)(sc2 + e) = *(const float4*)(c2g + e);
    }

    // A fragments: lane holds A[m = lr][k = ks*32 + q*8 .. +8] for rows
    // wid*64 + mt*16 + lr. 32 short8 = 128 VGPRs long-lived.
    short8 Ah[4][4], Al[4][4];
#pragma unroll
    for (int mt = 0; mt < 4; ++mt) {
        const float* rp = latent + (size_t)(row_block + wid * 64 + mt * 16 + lr) * D;
#pragma unroll
        for (int ks = 0; ks < 4; ++ks) {
            float v[8];
            *(float4*)(v)     = *(const float4*)(rp + ks * 32 + q * 8);
            *(float4*)(v + 4) = *(const float4*)(rp + ks * 32 + q * 8 + 4);
            split8(v, &Ah[mt][ks], &Al[mt][ks]);
        }
    }

    // argmax state over a = dot - 0.5*c2 (== argmin distance), 16 slots
    float b1[16], b2[16];
    int   bidx[16];
#pragma unroll
    for (int s = 0; s < 16; ++s) { b1[s] = -3.4e38f; b2[s] = -3.4e38f; bidx[s] = 0; }

    __syncthreads();   // full drain: chunk-0 stage + sc2 + A loads all visible

    for (int ch = 0; ch < NCHUNKS; ++ch) {
        const int buf = ch & 1;
        // issue next chunk's stage FIRST, then counted wait on current chunk's 8
        if (ch + 1 < NCHUNKS) {
            const unsigned short* sh = Bh_img + (size_t)(ch + 1) * (NCH * 128);
            const unsigned short* sl = Bl_img + (size_t)(ch + 1) * (NCH * 128);
#pragma unroll
            for (int i = 0; i < 4; ++i) {
                int e = (i * 256 + tid) * 8;
                gl_lds16(sh + e, &Bh[buf ^ 1][e]);
                gl_lds16(sl + e, &Bl[buf ^ 1][e]);
            }
            asm volatile("s_waitcnt vmcnt(8)" ::: "memory");  // cur done, next in flight
        } else {
            asm volatile("s_waitcnt vmcnt(0)" ::: "memory");
        }
        __builtin_amdgcn_s_barrier();

#pragma unroll
        for (int nt = 0; nt < 4; ++nt) {
            const int nl = nt * 16 + lr;
            const float mh = -0.5f * sc2[ch * NCH + nl];
            f32x4 acc[4];
#pragma unroll
            for (int mt = 0; mt < 4; ++mt) acc[mt] = (f32x4){mh, mh, mh, mh};
            __builtin_amdgcn_s_setprio(1);
#pragma unroll
            for (int ks = 0; ks < 4; ++ks) {
                const int xv = ((ks * 4) | q) ^ lr;     // swizzle: conflict-free
                const int e  = nl * 128 + xv * 8;
                short8 bh = *(const short8*)(&Bh[buf][e]);
                short8 bl = *(const short8*)(&Bl[buf][e]);
                // pass-major order: dependent MFMAs on the same acc are 4 apart
#pragma unroll
                for (int mt = 0; mt < 4; ++mt)
                    acc[mt] = __builtin_amdgcn_mfma_f32_16x16x32_bf16(Ah[mt][ks], bh, acc[mt], 0, 0, 0);
#pragma unroll
                for (int mt = 0; mt < 4; ++mt)
                    acc[mt] = __builtin_amdgcn_mfma_f32_16x16x32_bf16(Ah[mt][ks], bl, acc[mt], 0, 0, 0);
#pragma unroll
                for (int mt = 0; mt < 4; ++mt)
                    acc[mt] = __builtin_amdgcn_mfma_f32_16x16x32_bf16(Al[mt][ks], bh, acc[mt], 0, 0, 0);
            }
            __builtin_amdgcn_s_setprio(0);
            const int n_global = ch * NCH + nl;
            // med3 second-best epilogue (4 ops/score; validated in R2 run)
#pragma unroll
            for (int mt = 0; mt < 4; ++mt)
#pragma unroll
                for (int r = 0; r < 4; ++r) {
                    int slot = mt * 4 + r;
                    float a = acc[mt][r];
                    b2[slot]   = __builtin_amdgcn_fmed3f(a, b1[slot], b2[slot]);
                    bool gt    = a > b1[slot];
                    b1[slot]   = fmaxf(a, b1[slot]);
                    bidx[slot] = gt ? n_global : bidx[slot];
                }
        }
        __builtin_amdgcn_s_barrier();   // all reads of buf done before it's restaged
    }

    // butterfly over the 16 col-residue lanes (max semantics).
    // No index tie-break: equal scores -> gap 0 < margin -> exact refine.
#pragma unroll
    for (int m = 1; m <= 8; m <<= 1) {
#pragma unroll
        for (int s = 0; s < 16; ++s) {
            float oa = __shfl_xor(b1[s], m, 64);
            float ob = __shfl_xor(b2[s], m, 64);
            int   oi = __shfl_xor(bidx[s], m, 64);
            float mn = fminf(b1[s], oa);
            b2[s] = fmaxf(fmaxf(b2[s], ob), mn);
            bool take = oa > b1[s];
            b1[s]   = take ? oa : b1[s];
            bidx[s] = take ? oi : bidx[s];
        }
    }
    // slot s canonical in lane lr==s; row = wid*64 + (s>>2)*16 + q*4 + (s&3)
#pragma unroll
    for (int s = 0; s < 16; ++s) {
        if (lr == s) {
            int row = row_block + wid * 64 + (s >> 2) * 16 + q * 4 + (s & 3);
            out[row] = bidx[s];
            if (b1[s] - b2[s] < MARGIN_H) {
                int w = atomicAdd(counter, 1);
                if (w < WL_CAP) worklist[w] = row;
            }
        }
    }
}

// ---------------- fp64 refine ----------------

__global__ __launch_bounds__(256) void refine_fp64(
        const float* __restrict__ latent, const float* __restrict__ coords,
        const int* __restrict__ worklist, const int* __restrict__ counter,
        int wl_cap, int* __restrict__ out) {
    __shared__ float  xs[D];
    __shared__ double rv[256];
    __shared__ int    ri[256];

    int n = *counter;
    if (n > wl_cap) n = wl_cap;

    for (int wi = blockIdx.x; wi < n; wi += gridDim.x) {
        int row = worklist[wi];
        if (threadIdx.x < D)
            xs[threadIdx.x] = latent[(size_t)row * D + threadIdx.x];
        __syncthreads();

        double best = 1.0e300;
        int    bix  = 0;
        for (int c = threadIdx.x; c < C; c += 256) {
            const float4* cp = (const float4*)(coords + (size_t)c * D);
            // 4 independent accumulators: breaks the 512-deep dependent fma chain
            double s0 = 0.0, s1 = 0.0, s2 = 0.0, s3 = 0.0;
#pragma unroll 8
            for (int k4 = 0; k4 < 32; ++k4) {
                float4 v = cp[k4];
                double d0 = (double)xs[k4 * 4 + 0] - (double)v.x;
                double d1 = (double)xs[k4 * 4 + 1] - (double)v.y;
                double d2 = (double)xs[k4 * 4 + 2] - (double)v.z;
                double d3 = (double)xs[k4 * 4 + 3] - (double)v.w;
                s0 = fma(d0, d0, s0); s1 = fma(d1, d1, s1);
                s2 = fma(d2, d2, s2); s3 = fma(d3, d3, s3);
            }
            double s = (s0 + s1) + (s2 + s3);
            if (s < best) { best = s; bix = c; }
        }
        rv[threadIdx.x] = best;
        ri[threadIdx.x] = bix;
        __syncthreads();
        for (int off = 128; off > 0; off >>= 1) {
            if (threadIdx.x < off) {
                double ov = rv[threadIdx.x + off];
                int    oi = ri[threadIdx.x + off];
                if (ov < rv[threadIdx.x] ||
                    (ov == rv[threadIdx.x] && oi < ri[threadIdx.x])) {
                    rv[threadIdx.x] = ov;
                    ri[threadIdx.x] = oi;
                }
            }
            __syncthreads();
        }
        if (threadIdx.x == 0) out[row] = ri[0];
        __syncthreads();
    }
}

extern "C" void kernel_launch(void* const* d_in, const int* in_sizes, int n_in,
                              void* d_out, int out_size, void* d_ws, size_t ws_size,
                              hipStream_t stream) {
    const float* latent = (const float*)d_in[0];
    const float* coords = (const float*)d_in[1];
    int*         out    = (int*)d_out;

    char* ws = (char*)d_ws;
    float* c2      = (float*)ws;
    int*   counter = (int*)(ws + WS_CNT);
    int*   wl      = (int*)(ws + WS_WL);
    unsigned short* Bh = (unsigned short*)(ws + WS_BH);
    unsigned short* Bl = (unsigned short*)(ws + WS_BL);
    const int n_rows = in_sizes[0] / D;   // 131072

    prep_coords<<<(C * 16) / 256, 256, 0, stream>>>(coords, Bh, Bl, c2, counter);
    centroid_fast<<<n_rows / 256, 256, 0, stream>>>(latent, Bh, Bl, c2, out,
                                                    counter, wl);
    refine_fp64<<<608, 256, 0, stream>>>(latent, coords, wl, counter, WL_CAP, out);
}

// Round 5
// 276.290 us; speedup vs baseline: 1.2852x; 1.0593x over previous
//
#include <hip/hip_runtime.h>

// Centroids: argmin_c ||latent[r] - coords[c]||^2, 131072 rows x 2048 coords, D=128.
//
// R4/R5: int8 hi/lo 3-pass via mfma_i32_16x16x64_i8 (2x FLOP rate of bf16,
//     K=64/instr). a = qA(Ah + Al/128), b = qB(Bh + Bl/128), i32-exact:
//     dot = qA qB (I1 + I2/128), I1 = Ah.Bh, I2 = Ah.Bl + Al.Bh.
//     Dropped AlBl/16384 term + residuals: ~1e-3 std << MARGIN_H 0.01.
//     MFMA floor 99 -> 52 us. A-frags 128->64 VGPR, LDS 72->48 KB.
// R5 FIX: sqc table is 16 KB (float2 x 2048) but R4 staged only 8 KB ->
//     chunks 16..31 used garbage {qB,-c2/2} (absmax 2040). Loop 2 -> 4 iters.
// Kept from R1-R3 (validated): 64-row waves, dbuf LDS w/ global_load_lds w=16
//     + counted vmcnt, de-phase entry sleep, setprio(1) around MFMA, med3
//     second-best epilogue, no-tiebreak butterfly, fp64 refine (margin net).
//
// ws layout (bytes): 0 qc2 (16KB) | 16384 counter | 32768 worklist (128KB) |
//                    262144 Bh (256KB) | 524288 Bl (256KB) | end 786432

constexpr int D = 128;
constexpr int C = 2048;
constexpr int NCH = 64;            // coords per chunk
constexpr int NCHUNKS = C / NCH;   // 32
constexpr float MARGIN_H = 0.01f;  // half-scale; i8 hi/lo 4-sigma err ~4e-3
constexpr int WL_CAP = 32768;

constexpr size_t WS_CNT = 16384;
constexpr size_t WS_WL  = 32768;
constexpr size_t WS_BH  = 262144;
constexpr size_t WS_BL  = 524288;

typedef __attribute__((ext_vector_type(4))) int   i32x4;
typedef unsigned int u32;

__device__ __forceinline__ int pack4(int a0, int a1, int a2, int a3) {
    return (int)(((u32)a0 & 255u) | (((u32)a1 & 255u) << 8) |
                 (((u32)a2 & 255u) << 16) | (((u32)a3 & 255u) << 24));
}

// quantize v -> hi (|h|<=127), lo (|l|<=64): v = h*qa + l*qa/128 + eps
__device__ __forceinline__ void q2(float v, float qa, float inv, float inv128,
                                   int* h, int* l) {
    float hf = __builtin_rintf(v * inv);
    *h = (int)hf;
    float r = fmaf(-hf, qa, v);
    *l = (int)__builtin_rintf(r * inv128);
}

// async global->LDS, 16B per lane (wave-uniform base + lane*16: contiguous).
__device__ __forceinline__ void gl_lds16(const void* g, void* l) {
    __builtin_amdgcn_global_load_lds(
        (const __attribute__((address_space(1))) u32*)g,
        (__attribute__((address_space(3))) u32*)l, 16, 0, 0);
}

// ---------------- prep: int8 B images + {qB, -c2/2} ----------------
// 4 threads per coord; thread part p handles elems p*32..p*32+31 (granules
// g8 = 2p, 2p+1). Image granule placement: pos = g8 ^ (nl&7), nl = c&63.
__global__ void prep_coords(const float* __restrict__ coords,
                            signed char* __restrict__ Bh,
                            signed char* __restrict__ Bl,
                            float2* __restrict__ qc2, int* __restrict__ counter) {
    int t = blockIdx.x * blockDim.x + threadIdx.x;
    if (t == 0) *counter = 0;
    if (t >= C * 4) return;
    int c = t >> 2, p = t & 3;
    float v[32];
#pragma unroll
    for (int i = 0; i < 8; ++i)
        *(float4*)(v + i * 4) = *(const float4*)(coords + (size_t)c * D + p * 32 + i * 4);
    float amax = 0.f, ss = 0.f;
#pragma unroll
    for (int j = 0; j < 32; ++j) {
        amax = fmaxf(amax, fabsf(v[j]));
        ss = fmaf(v[j], v[j], ss);
    }
#pragma unroll
    for (int m = 1; m <= 2; m <<= 1) {
        amax = fmaxf(amax, __shfl_xor(amax, m, 64));
        ss += __shfl_xor(ss, m, 64);
    }
    float qb = fmaxf(amax, 1e-30f) * (1.f / 127.f);
    float inv = 127.f / fmaxf(amax, 1e-30f);
    float inv128 = inv * 128.f;

    int ch = c >> 6, nl = c & 63;
    size_t cbase = (size_t)ch * (NCH * 128) + (size_t)nl * 128;
#pragma unroll
    for (int g = 0; g < 2; ++g) {        // two 16-elem granules
        int g8 = p * 2 + g;
        int hw[4], lw[4];
#pragma unroll
        for (int w = 0; w < 4; ++w) {
            int h0, l0, h1, l1, h2, l2, h3, l3;
            q2(v[g * 16 + w * 4 + 0], qb, inv, inv128, &h0, &l0);
            q2(v[g * 16 + w * 4 + 1], qb, inv, inv128, &h1, &l1);
            q2(v[g * 16 + w * 4 + 2], qb, inv, inv128, &h2, &l2);
            q2(v[g * 16 + w * 4 + 3], qb, inv, inv128, &h3, &l3);
            hw[w] = pack4(h0, h1, h2, h3);
            lw[w] = pack4(l0, l1, l2, l3);
        }
        size_t off = cbase + (size_t)(g8 ^ (nl & 7)) * 16;
        *(i32x4*)(Bh + off) = (i32x4){hw[0], hw[1], hw[2], hw[3]};
        *(i32x4*)(Bl + off) = (i32x4){lw[0], lw[1], lw[2], lw[3]};
    }
    if (p == 0) qc2[c] = make_float2(qb, -0.5f * ss);
}

// ---------------- main kernel ----------------

__global__ __launch_bounds__(256, 2) void centroid_fast(
        const float* __restrict__ latent,
        const signed char* __restrict__ Bh_img,
        const signed char* __restrict__ Bl_img,
        const float2* __restrict__ qc2g,
        int* __restrict__ out,
        int* __restrict__ counter,
        int* __restrict__ worklist) {
    // dbuf 2x8KB hi + 2x8KB lo + {qB,-c2/2} table 16KB = 48 KB -> 2 blocks/CU
    __shared__ __align__(16) signed char Bh[2][NCH * 128], Bl[2][NCH * 128];
    __shared__ __align__(16) float2 sqc[C];

    const int tid  = threadIdx.x;
    const int wid  = tid >> 6;            // wave 0..3 -> rows wid*64..wid*64+63
    const int lane = tid & 63;
    const int q    = lane >> 4, lr = lane & 15;
    const int row_block = blockIdx.x * 256;

    // de-phase co-resident blocks (validated R3): one-time ~7k-cyc sleep
    if ((blockIdx.x ^ (blockIdx.x >> 8)) & 1) {
#pragma unroll
        for (int i = 0; i < 14; ++i) __builtin_amdgcn_s_sleep(8);
    }

    // ---- prologue: stage chunk 0 (async), qc2 table ----
#pragma unroll
    for (int i = 0; i < 2; ++i) {
        int e = (i * 256 + tid) * 16;
        gl_lds16(Bh_img + e, &Bh[0][e]);
        gl_lds16(Bl_img + e, &Bl[0][e]);
    }
    // R5 FIX: full 16 KB (2048 float2) -> 4 iterations of 16 B/thread
#pragma unroll
    for (int i = 0; i < 4; ++i) {
        int e = (i * 256 + tid) * 2;
        *(float4*)(&sqc[e]) = *(const float4*)(&qc2g[e]);
    }

    // ---- A fragments: int8 hi/lo. Lane holds rows wid*64+mt*16+lr,
    // k = kstep*64 + q*16 + 0..15 -> i32x4 per (mt,kstep). 64 VGPRs total.
    i32x4 Ah[4][2], Al[4][2];
    float qAr[4][4];                     // qA for epilogue rows mt*16+q*4+r
#pragma unroll
    for (int mt = 0; mt < 4; ++mt) {
        const float* rp = latent + (size_t)(row_block + wid * 64 + mt * 16 + lr) * D;
        float v[32];
#pragma unroll
        for (int ks = 0; ks < 2; ++ks)
#pragma unroll
            for (int i = 0; i < 4; ++i)
                *(float4*)(v + ks * 16 + i * 4) =
                    *(const float4*)(rp + ks * 64 + q * 16 + i * 4);
        float amax = 0.f;
#pragma unroll
        for (int j = 0; j < 32; ++j) amax = fmaxf(amax, fabsf(v[j]));
        amax = fmaxf(amax, __shfl_xor(amax, 16, 64));
        amax = fmaxf(amax, __shfl_xor(amax, 32, 64));
        float qa = fmaxf(amax, 1e-30f) * (1.f / 127.f);
        float inv = 127.f / fmaxf(amax, 1e-30f);
        float inv128 = inv * 128.f;
#pragma unroll
        for (int ks = 0; ks < 2; ++ks) {
            int hw[4], lw[4];
#pragma unroll
            for (int w = 0; w < 4; ++w) {
                int h0, l0, h1, l1, h2, l2, h3, l3;
                q2(v[ks * 16 + w * 4 + 0], qa, inv, inv128, &h0, &l0);
                q2(v[ks * 16 + w * 4 + 1], qa, inv, inv128, &h1, &l1);
                q2(v[ks * 16 + w * 4 + 2], qa, inv, inv128, &h2, &l2);
                q2(v[ks * 16 + w * 4 + 3], qa, inv, inv128, &h3, &l3);
                hw[w] = pack4(h0, h1, h2, h3);
                lw[w] = pack4(l0, l1, l2, l3);
            }
            Ah[mt][ks] = (i32x4){hw[0], hw[1], hw[2], hw[3]};
            Al[mt][ks] = (i32x4){lw[0], lw[1], lw[2], lw[3]};
        }
        // broadcast qa from lr-lanes to (q*4+r) epilogue rows
#pragma unroll
        for (int r = 0; r < 4; ++r)
            qAr[mt][r] = __shfl(qa, (lane & 48) | (q * 4 + r), 64);
    }

    // argmax state over a = dot - 0.5*c2 (== argmin distance), 16 slots
    float b1[16], b2[16];
    int   bidx[16];
#pragma unroll
    for (int s = 0; s < 16; ++s) { b1[s] = -3.4e38f; b2[s] = -3.4e38f; bidx[s] = 0; }

    __syncthreads();   // full drain: chunk-0 stage + sqc visible

    for (int ch = 0; ch < NCHUNKS; ++ch) {
        const int buf = ch & 1;
        const int chbase = ch * NCH;
        // issue next chunk's stage FIRST, then counted wait on current's 4
        if (ch + 1 < NCHUNKS) {
            const signed char* sh = Bh_img + (size_t)(ch + 1) * (NCH * 128);
            const signed char* sl = Bl_img + (size_t)(ch + 1) * (NCH * 128);
#pragma unroll
            for (int i = 0; i < 2; ++i) {
                int e = (i * 256 + tid) * 16;
                gl_lds16(sh + e, &Bh[buf ^ 1][e]);
                gl_lds16(sl + e, &Bl[buf ^ 1][e]);
            }
            asm volatile("s_waitcnt vmcnt(4)" ::: "memory");
        } else {
            asm volatile("s_waitcnt vmcnt(0)" ::: "memory");
        }
        __builtin_amdgcn_s_barrier();

#pragma unroll
        for (int nt = 0; nt < 4; ++nt) {
            const int nl = nt * 16 + lr;
            const float2 qc = sqc[chbase + nl];   // {qB, -c2/2}
            i32x4 I1[4], I2[4];
#pragma unroll
            for (int mt = 0; mt < 4; ++mt) {
                I1[mt] = (i32x4){0, 0, 0, 0};
                I2[mt] = (i32x4){0, 0, 0, 0};
            }
            __builtin_amdgcn_s_setprio(1);
#pragma unroll
            for (int ks = 0; ks < 2; ++ks) {
                const int e = nl * 128 + (((ks << 2) | q) ^ (lr & 7)) * 16;
                i32x4 bh = *(const i32x4*)(&Bh[buf][e]);
                i32x4 bl = *(const i32x4*)(&Bl[buf][e]);
#pragma unroll
                for (int mt = 0; mt < 4; ++mt)
                    I1[mt] = __builtin_amdgcn_mfma_i32_16x16x64_i8(Ah[mt][ks], bh, I1[mt], 0, 0, 0);
#pragma unroll
                for (int mt = 0; mt < 4; ++mt)
                    I2[mt] = __builtin_amdgcn_mfma_i32_16x16x64_i8(Ah[mt][ks], bl, I2[mt], 0, 0, 0);
#pragma unroll
                for (int mt = 0; mt < 4; ++mt)
                    I2[mt] = __builtin_amdgcn_mfma_i32_16x16x64_i8(Al[mt][ks], bh, I2[mt], 0, 0, 0);
            }
            __builtin_amdgcn_s_setprio(0);
            const int n_global = chbase + nl;
#pragma unroll
            for (int mt = 0; mt < 4; ++mt)
#pragma unroll
                for (int r = 0; r < 4; ++r) {
                    int slot = mt * 4 + r;
                    float x = fmaf((float)I2[mt][r], 0.0078125f, (float)I1[mt][r]);
                    float a = fmaf(qAr[mt][r], x * qc.x, qc.y);
                    b2[slot]   = __builtin_amdgcn_fmed3f(a, b1[slot], b2[slot]);
                    bool gt    = a > b1[slot];
                    b1[slot]   = fmaxf(a, b1[slot]);
                    bidx[slot] = gt ? n_global : bidx[slot];
                }
        }
        __builtin_amdgcn_s_barrier();   // all reads of buf done before restage
    }

    // butterfly over the 16 col-residue lanes (max semantics, no tie-break:
    // ties -> gap 0 < margin -> exact refine resolves)
#pragma unroll
    for (int m = 1; m <= 8; m <<= 1) {
#pragma unroll
        for (int s = 0; s < 16; ++s) {
            float oa = __shfl_xor(b1[s], m, 64);
            float ob = __shfl_xor(b2[s], m, 64);
            int   oi = __shfl_xor(bidx[s], m, 64);
            float mn = fminf(b1[s], oa);
            b2[s] = fmaxf(fmaxf(b2[s], ob), mn);
            bool take = oa > b1[s];
            b1[s]   = take ? oa : b1[s];
            bidx[s] = take ? oi : bidx[s];
        }
    }
    // slot s canonical in lane lr==s; row = wid*64 + (s>>2)*16 + q*4 + (s&3)
#pragma unroll
    for (int s = 0; s < 16; ++s) {
        if (lr == s) {
            int row = row_block + wid * 64 + (s >> 2) * 16 + q * 4 + (s & 3);
            out[row] = bidx[s];
            if (b1[s] - b2[s] < MARGIN_H) {
                int w = atomicAdd(counter, 1);
                if (w < WL_CAP) worklist[w] = row;
            }
        }
    }
}

// ---------------- fp64 refine ----------------

__global__ __launch_bounds__(256) void refine_fp64(
        const float* __restrict__ latent, const float* __restrict__ coords,
        const int* __restrict__ worklist, const int* __restrict__ counter,
        int wl_cap, int* __restrict__ out) {
    __shared__ float  xs[D];
    __shared__ double rv[256];
    __shared__ int    ri[256];

    int n = *counter;
    if (n > wl_cap) n = wl_cap;

    for (int wi = blockIdx.x; wi < n; wi += gridDim.x) {
        int row = worklist[wi];
        if (threadIdx.x < D)
            xs[threadIdx.x] = latent[(size_t)row * D + threadIdx.x];
        __syncthreads();

        double best = 1.0e300;
        int    bix  = 0;
        for (int c = threadIdx.x; c < C; c += 256) {
            const float4* cp = (const float4*)(coords + (size_t)c * D);
            double s0 = 0.0, s1 = 0.0, s2 = 0.0, s3 = 0.0;
#pragma unroll 8
            for (int k4 = 0; k4 < 32; ++k4) {
                float4 v = cp[k4];
                double d0 = (double)xs[k4 * 4 + 0] - (double)v.x;
                double d1 = (double)xs[k4 * 4 + 1] - (double)v.y;
                double d2 = (double)xs[k4 * 4 + 2] - (double)v.z;
                double d3 = (double)xs[k4 * 4 + 3] - (double)v.w;
                s0 = fma(d0, d0, s0); s1 = fma(d1, d1, s1);
                s2 = fma(d2, d2, s2); s3 = fma(d3, d3, s3);
            }
            double s = (s0 + s1) + (s2 + s3);
            if (s < best) { best = s; bix = c; }
        }
        rv[threadIdx.x] = best;
        ri[threadIdx.x] = bix;
        __syncthreads();
        for (int off = 128; off > 0; off >>= 1) {
            if (threadIdx.x < off) {
                double ov = rv[threadIdx.x + off];
                int    oi = ri[threadIdx.x + off];
                if (ov < rv[threadIdx.x] ||
                    (ov == rv[threadIdx.x] && oi < ri[threadIdx.x])) {
                    rv[threadIdx.x] = ov;
                    ri[threadIdx.x] = oi;
                }
            }
            __syncthreads();
        }
        if (threadIdx.x == 0) out[row] = ri[0];
        __syncthreads();
    }
}

extern "C" void kernel_launch(void* const* d_in, const int* in_sizes, int n_in,
                              void* d_out, int out_size, void* d_ws, size_t ws_size,
                              hipStream_t stream) {
    const float* latent = (const float*)d_in[0];
    const float* coords = (const float*)d_in[1];
    int*         out    = (int*)d_out;

    char* ws = (char*)d_ws;
    float2* qc2    = (float2*)ws;
    int*    counter = (int*)(ws + WS_CNT);
    int*    wl      = (int*)(ws + WS_WL);
    signed char* Bh = (signed char*)(ws + WS_BH);
    signed char* Bl = (signed char*)(ws + WS_BL);
    const int n_rows = in_sizes[0] / D;   // 131072

    prep_coords<<<(C * 4) / 256, 256, 0, stream>>>(coords, Bh, Bl, qc2, counter);
    centroid_fast<<<n_rows / 256, 256, 0, stream>>>(latent, Bh, Bl, qc2, out,
                                                    counter, wl);
    refine_fp64<<<608, 256, 0, stream>>>(latent, coords, wl, counter, WL_CAP, out);
}